// Round 7
// baseline (136.785 us; speedup 1.0000x reference)
//
#include <hip/hip_runtime.h>
#include <hip/hip_bf16.h>
#include <stdint.h>

// Problem constants (fixed by reference)
#define B_  4
#define N_  8192
#define M_  8192
#define D_  64
#define KP  96    // padded K: 64 data + (norm_hi, norm_lo, 1, 1) + 28 zeros
#define NT_ 64    // N_/128
#define MT_ 64    // M_/128
#define RBN ((B_ * N_) / 16)   // 2048 16-row blocks on A side

typedef __attribute__((ext_vector_type(8))) short bhalf8;   // 8 bf16 (MFMA A/B frag)
typedef __attribute__((ext_vector_type(4))) float f32x4;    // MFMA C/D frag

// ---- workspace layout (bytes) ----
// A'/B': bf16, fragment-chunk order: chunk(rb, ks=0..2, lane=q*16+c) = row (rb*16+c),
//        k = ks*32 + q*8 .. +7; stored at ((rb*3+ks)*64 + lane)*8 elems -> lane-contiguous 1KB loads.
// K extension fuses norms: A' row n = (-2f[n], nh, nl, 1, 1, 0...), B' row m = (f_[m], 1, 1, nh2, nl2, 0...)
//   => A'.B' = full squared distance straight out of MFMA.
static const size_t OFF_A  = 0;
static const size_t OFF_B  = (size_t)B_ * N_ * KP * 2;                   // 6,291,456
static const size_t OFF_RP = OFF_B + (size_t)B_ * M_ * KP * 2;           // 12,582,912
static const size_t OFF_CP = OFF_RP + (size_t)B_ * NT_ * 8 * 128 * 4;    // 13,631,488
// end of CP: + 4*64*64*128*4 = 22,020,096

__device__ __forceinline__ short bf16bits(float x) {
    union { __hip_bfloat16 h; unsigned short u; } cv;
    cv.h = __float2bfloat16(x);
    return (short)cv.u;
}

// ---------------- prep: build K=96 fused-norm fragment layout; zero the output accumulator ----------------
__global__ __launch_bounds__(256) void chamfer_prep(
        const float* __restrict__ f, const float* __restrict__ f2,
        unsigned short* __restrict__ Ap, unsigned short* __restrict__ Bp,
        float* __restrict__ out) {
    const int tid = threadIdx.x;
    if (blockIdx.x == 0 && tid == 0) out[0] = 0.f;   // finalize atomicAdds into this
    const int w = blockIdx.x * 4 + (tid >> 6);       // 16-row block id, 0..4095
    const int lane = tid & 63;
    const int q = lane >> 4, c = lane & 15;
    const bool isA = w < RBN;
    const int rb = isA ? w : w - RBN;
    const float* src = isA ? f : f2;
    unsigned short* dst = isA ? Ap : Bp;
    const float scale = isA ? -2.0f : 1.0f;          // fold the -2 into A; exact in bf16

    const float* row = src + ((size_t)rb * 16 + c) * 64;
    f32x4 u0 = *(const f32x4*)(row + q * 8);
    f32x4 u1 = *(const f32x4*)(row + q * 8 + 4);
    f32x4 u2 = *(const f32x4*)(row + 32 + q * 8);
    f32x4 u3 = *(const f32x4*)(row + 32 + q * 8 + 4);

    float ss = 0.f;
    #pragma unroll
    for (int k = 0; k < 4; k++)
        ss += u0[k] * u0[k] + u1[k] * u1[k] + u2[k] * u2[k] + u3[k] * u3[k];
    ss += __shfl_xor(ss, 16, 64);
    ss += __shfl_xor(ss, 32, 64);                    // full ||row c||^2 in every lane

    bhalf8 o0, o1;
    #pragma unroll
    for (int k = 0; k < 4; k++) {
        o0[k]     = bf16bits(u0[k] * scale);
        o0[4 + k] = bf16bits(u1[k] * scale);
        o1[k]     = bf16bits(u2[k] * scale);
        o1[4 + k] = bf16bits(u3[k] * scale);
    }
    bhalf8 o2 = {0, 0, 0, 0, 0, 0, 0, 0};            // k=64..95 zeros except q==0 lanes
    if (q == 0) {
        float nh = __bfloat162float(__float2bfloat16(ss));  // hi part, exact in bf16
        float nl = ss - nh;                                  // residual
        const short one = 0x3F80;                            // bf16 1.0
        if (isA) { o2[0] = bf16bits(nh); o2[1] = bf16bits(nl); o2[2] = one; o2[3] = one; }
        else     { o2[0] = one; o2[1] = one; o2[2] = bf16bits(nh); o2[3] = bf16bits(nl); }
    }
    *(bhalf8*)(dst + ((size_t)(rb * 3 + 0) * 64 + lane) * 8) = o0;
    *(bhalf8*)(dst + ((size_t)(rb * 3 + 1) * 64 + lane) * 8) = o1;
    *(bhalf8*)(dst + ((size_t)(rb * 3 + 2) * 64 + lane) * 8) = o2;
}

// ---------------- tile kernel: 128-row waves, 16-col half-steps ----------------
// grid (mc=8, nt=64, b=4) = 2048 blocks, 4 waves/block split by COLUMN quarter (wc).
// Each wave: A = all 128 rows persistent in registers (af[8][3], 96 VGPR); per half-step
// stream one 16-col B-tile (3 loads, 24 MFMA), row-min into registers, col-min in-lane
// (32 elems) + 2 shfl over q + fire-and-forget store. No in-loop LDS, no barriers.
__global__ __launch_bounds__(256, 2) void chamfer_tile(
        const unsigned short* __restrict__ Ap, const unsigned short* __restrict__ Bp,
        float* __restrict__ rowpart, float* __restrict__ colpart) {
    const int mc = blockIdx.x;   // 0..7 : 8-tile mt chunk
    const int nt = blockIdx.y;   // 0..63
    const int b  = blockIdx.z;   // 0..3
    const int tid = threadIdx.x;
    const int wc = tid >> 6, lane = tid & 63;   // wc = column quarter 0..3
    const int q = lane >> 4, c = lane & 15;

    // A fragments: rows nt*128 + i*16 + c, 3 k-steps each. Persistent.
    const unsigned short* ap = Ap + (size_t)(b * 512 + nt * 8) * 1536 + lane * 8;
    bhalf8 af[8][3];
    #pragma unroll
    for (int i = 0; i < 8; i++)
        #pragma unroll
        for (int ks = 0; ks < 3; ks++)
            af[i][ks] = *(const bhalf8*)(ap + (size_t)(i * 3 + ks) * 512);

    f32x4 rv[8];                 // running row-min, rows i*16+q*4+r
    #pragma unroll
    for (int i = 0; i < 8; i++) rv[i] = (f32x4){3.0e38f, 3.0e38f, 3.0e38f, 3.0e38f};

    const f32x4 zero4 = {0.f, 0.f, 0.f, 0.f};

    // half-step h (0..15): mt = mc*8 + h/2, B row-block rb = mt*8 + wc*2 + (h&1) -> 16 cols
    auto loadB = [&](int h, bhalf8 (&bf)[3]) {
        const int rb = b * 512 + (mc * 8 + (h >> 1)) * 8 + wc * 2 + (h & 1);
        const unsigned short* p = Bp + (size_t)rb * 1536 + lane * 8;
        bf[0] = *(const bhalf8*)(p);
        bf[1] = *(const bhalf8*)(p + 512);
        bf[2] = *(const bhalf8*)(p + 1024);
    };

    auto process = [&](int h, bhalf8 (&bf)[3]) {
        f32x4 acc[8];
        #pragma unroll
        for (int i = 0; i < 8; i++)
            acc[i] = __builtin_amdgcn_mfma_f32_16x16x32_bf16(af[i][0], bf[0], zero4, 0, 0, 0);
        #pragma unroll
        for (int ks = 1; ks < 3; ks++)
            #pragma unroll
            for (int i = 0; i < 8; i++)
                acc[i] = __builtin_amdgcn_mfma_f32_16x16x32_bf16(af[i][ks], bf[ks], acc[i], 0, 0, 0);
        // acc[i][r] = d(row nt*128+i*16+q*4+r, col mt*128+wc*32+(h&1)*16+c)

        // row-min into persistent registers (32 v_min)
        #pragma unroll
        for (int i = 0; i < 8; i++)
            #pragma unroll
            for (int r = 0; r < 4; r++)
                rv[i][r] = fminf(rv[i][r], acc[i][r]);

        // col-min: in-lane chain over 32 elements (rows 16i+4q+r), min3-friendly
        float t = fminf(fminf(acc[0][0], acc[0][1]), fminf(acc[0][2], acc[0][3]));
        #pragma unroll
        for (int i = 1; i < 8; i++) {
            t = fminf(fminf(t, acc[i][0]), acc[i][1]);
            t = fminf(fminf(t, acc[i][2]), acc[i][3]);
        }
        // combine the 4 q-groups (rows subsets) -> full 128-row col-min
        t = fminf(t, __shfl_xor(t, 16, 64));
        t = fminf(t, __shfl_xor(t, 32, 64));
        if (q == 0) {
            const int mt = mc * 8 + (h >> 1);
            colpart[((size_t)(b * 64 + mt) * 64 + nt) * 128 + wc * 32 + (h & 1) * 16 + c] = t;
        }
    };

    bhalf8 bf[2][3];
    loadB(0, bf[0]);
    #pragma unroll 2
    for (int h = 0; h < 16; h++) {
        if (h + 1 < 16) loadB(h + 1, bf[(h + 1) & 1]);
        process(h, bf[h & 1]);
    }

    // row combine across the 64 (wc,c) column-owner lane groups (once per block)
    __shared__ __align__(16) float rowbuf[64][132];
    #pragma unroll
    for (int i = 0; i < 8; i++)
        *(f32x4*)&rowbuf[wc * 16 + c][i * 16 + q * 4] = rv[i];
    __syncthreads();
    if (tid < 128) {
        float v = rowbuf[0][tid];
        #pragma unroll 8
        for (int cc = 1; cc < 64; cc++) v = fminf(v, rowbuf[cc][tid]);
        rowpart[((size_t)(b * 64 + nt) * 8 + mc) * 128 + tid] = v;
    }
}

// ---------------- finalize: global min over partials + mean, atomicAdd scalar ----------------
__global__ __launch_bounds__(256) void chamfer_finalize(
        const float* __restrict__ rowpart, const float* __restrict__ colpart,
        float* __restrict__ out) {
    const int blk = blockIdx.x;      // 0..255 row side (b,nt); 256..511 col side (b,mt)
    const int tid = threadIdx.x;
    float val = 0.f, scale;
    __shared__ float hbuf[128];

    if (blk < 256) {
        scale = 1.0f / ((float)B_ * (float)N_);
        if (tid < 128) {
            const float* rp = rowpart + (size_t)blk * 8 * 128;
            float m = rp[tid];
            #pragma unroll
            for (int k = 1; k < 8; k++) m = fminf(m, rp[k * 128 + tid]);
            val = m;
        }
    } else {
        scale = 1.0f / ((float)B_ * (float)M_);
        const float* cp = colpart + (size_t)(blk - 256) * 64 * 128;
        const int t = tid & 127, h = tid >> 7;
        float m = 3.0e38f;
        for (int ntb = h * 32; ntb < h * 32 + 32; ntb++)
            m = fminf(m, cp[(size_t)ntb * 128 + t]);
        if (h == 1) hbuf[t] = m;
        __syncthreads();
        if (h == 0) val = fminf(m, hbuf[t]);
    }

    __shared__ float sb[256];
    sb[tid] = val * scale;
    __syncthreads();
    for (int s = 128; s > 0; s >>= 1) {
        if (tid < s) sb[tid] += sb[tid + s];
        __syncthreads();
    }
    if (tid == 0) atomicAdd(out, sb[0]);
}

extern "C" void kernel_launch(void* const* d_in, const int* in_sizes, int n_in,
                              void* d_out, int out_size, void* d_ws, size_t ws_size,
                              hipStream_t stream) {
    const float* f  = (const float*)d_in[0];
    const float* f2 = (const float*)d_in[1];
    char* ws = (char*)d_ws;
    unsigned short* Ap = (unsigned short*)(ws + OFF_A);
    unsigned short* Bp = (unsigned short*)(ws + OFF_B);
    float* rowpart = (float*)(ws + OFF_RP);
    float* colpart = (float*)(ws + OFF_CP);
    float* out     = (float*)d_out;

    // prep: 4096 waves (one per 16-row block) -> 1024 blocks; also zeroes out[0]
    chamfer_prep<<<dim3(1024), dim3(256), 0, stream>>>(f, f2, Ap, Bp, out);

    // main: 2048 blocks, 128-row waves, 16 half-steps
    chamfer_tile<<<dim3(8, NT_, B_), dim3(256), 0, stream>>>(Ap, Bp, rowpart, colpart);

    // finalize: mins + means + atomicAdd into out
    chamfer_finalize<<<dim3(512), dim3(256), 0, stream>>>(rowpart, colpart, out);
}

// Round 8
// 119.861 us; speedup vs baseline: 1.1412x; 1.1412x over previous
//
#include <hip/hip_runtime.h>
#include <hip/hip_bf16.h>
#include <stdint.h>

// Problem constants (fixed by reference)
#define B_  4
#define N_  8192
#define M_  8192
#define D_  64
#define KP  96    // padded K: 64 data + (norm_hi, norm_lo, 1, 1) + 28 zeros
#define NT_ 64    // N_/128
#define MT_ 64    // M_/128
#define RBN ((B_ * N_) / 16)   // 2048 16-row blocks on A side
#define INF_BITS 0x7F800000    // +inf float bits; signed-int min == float min for our range

typedef __attribute__((ext_vector_type(8))) short bhalf8;   // 8 bf16 (MFMA A/B frag)
typedef __attribute__((ext_vector_type(4))) float f32x4;    // MFMA C/D frag

// ---- workspace layout (bytes) ----
// A'/B': bf16, fragment-chunk order: chunk(rb, ks=0..2, lane=q*16+c) = row (rb*16+c),
//        k = ks*32 + q*8 .. +7; at ((rb*3+ks)*64 + lane)*8 elems -> lane-contiguous 1KB loads.
// K extension fuses norms: A' row n = (-2f[n], nh, nl, 1, 1, 0...), B' row m = (f_[m], 1, 1, nh2, nl2, 0...)
//   => A'.B' = full squared distance straight out of MFMA.
// rowglob/colglob: per-point global mins as float BIT PATTERNS (int), accumulated with atomicMin.
static const size_t OFF_A  = 0;
static const size_t OFF_B  = (size_t)B_ * N_ * KP * 2;                   // 6,291,456
static const size_t OFF_RG = OFF_B + (size_t)B_ * M_ * KP * 2;           // 12,582,912
static const size_t OFF_CG = OFF_RG + (size_t)B_ * N_ * 4;               // +128 KB
// end: OFF_CG + 128 KB

__device__ __forceinline__ short bf16bits(float x) {
    union { __hip_bfloat16 h; unsigned short u; } cv;
    cv.h = __float2bfloat16(x);
    return (short)cv.u;
}
__device__ __forceinline__ float min3f(float a, float b, float c) {
    return fminf(fminf(a, b), c);   // -> v_min3_f32
}

// ---------------- prep: K=96 fused-norm fragment layout; init global min buffers + out ----------------
__global__ __launch_bounds__(256) void chamfer_prep(
        const float* __restrict__ f, const float* __restrict__ f2,
        unsigned short* __restrict__ Ap, unsigned short* __restrict__ Bp,
        int* __restrict__ minbuf, float* __restrict__ out) {
    const int tid = threadIdx.x;
    const int gid = blockIdx.x * 256 + tid;
    if (gid == 0) out[0] = 0.f;                      // finalize atomicAdds into this
    if (gid < 65536) minbuf[gid] = INF_BITS;         // rowglob(32K ints) + colglob(32K ints)

    const int w = gid >> 6;                          // 16-row block id, 0..4095
    const int lane = tid & 63;
    const int q = lane >> 4, c = lane & 15;
    const bool isA = w < RBN;
    const int rb = isA ? w : w - RBN;
    const float* src = isA ? f : f2;
    unsigned short* dst = isA ? Ap : Bp;
    const float scale = isA ? -2.0f : 1.0f;          // fold the -2 into A; exact in bf16

    const float* row = src + ((size_t)rb * 16 + c) * 64;
    f32x4 u0 = *(const f32x4*)(row + q * 8);
    f32x4 u1 = *(const f32x4*)(row + q * 8 + 4);
    f32x4 u2 = *(const f32x4*)(row + 32 + q * 8);
    f32x4 u3 = *(const f32x4*)(row + 32 + q * 8 + 4);

    float ss = 0.f;
    #pragma unroll
    for (int k = 0; k < 4; k++)
        ss += u0[k] * u0[k] + u1[k] * u1[k] + u2[k] * u2[k] + u3[k] * u3[k];
    ss += __shfl_xor(ss, 16, 64);
    ss += __shfl_xor(ss, 32, 64);                    // full ||row c||^2 in every lane

    bhalf8 o0, o1;
    #pragma unroll
    for (int k = 0; k < 4; k++) {
        o0[k]     = bf16bits(u0[k] * scale);
        o0[4 + k] = bf16bits(u1[k] * scale);
        o1[k]     = bf16bits(u2[k] * scale);
        o1[4 + k] = bf16bits(u3[k] * scale);
    }
    bhalf8 o2 = {0, 0, 0, 0, 0, 0, 0, 0};            // k=64..95 zeros except q==0 lanes
    if (q == 0) {
        float nh = __bfloat162float(__float2bfloat16(ss));  // hi part, exact in bf16
        float nl = ss - nh;                                  // residual
        const short one = 0x3F80;                            // bf16 1.0
        if (isA) { o2[0] = bf16bits(nh); o2[1] = bf16bits(nl); o2[2] = one; o2[3] = one; }
        else     { o2[0] = one; o2[1] = one; o2[2] = bf16bits(nh); o2[3] = bf16bits(nl); }
    }
    *(bhalf8*)(dst + ((size_t)(rb * 3 + 0) * 64 + lane) * 8) = o0;
    *(bhalf8*)(dst + ((size_t)(rb * 3 + 1) * 64 + lane) * 8) = o1;
    *(bhalf8*)(dst + ((size_t)(rb * 3 + 2) * 64 + lane) * 8) = o2;
}

// ---------------- tile kernel: wait-free K-loop, conflict-free LDS atomic mins ----------------
// grid (mc=8, nt=64, b=4) = 2048 blocks; wave tile 64 rows x 32 cols/step, 16 steps.
// Row-min in registers; col-min via per-q-slot ds_min (no same-address or bank conflicts);
// B-frags double-buffered via incremental pointers; zero in-loop stores/barriers.
__global__ __launch_bounds__(256) void chamfer_tile(
        const unsigned short* __restrict__ Ap, const unsigned short* __restrict__ Bp,
        int* __restrict__ rowglob, int* __restrict__ colglob) {
    const int mc = blockIdx.x;   // 0..7 : 8-tile mt chunk
    const int nt = blockIdx.y;   // 0..63
    const int b  = blockIdx.z;   // 0..3
    const int tid = threadIdx.x;
    const int wave = tid >> 6, lane = tid & 63;
    const int wr = wave >> 1, wc = wave & 1;
    const int q = lane >> 4, c = lane & 15;

    // q-slot col mins: stride 1064 words (1064%32==8 -> bank 8q+col: <=2-way, free)
    __shared__ int colmin[4][1064];   // [q][mtl*132 + col], col 0..127, mtl 0..7
    __shared__ int rowmin[128];
    #pragma unroll
    for (int k = 0; k < 17; k++) {
        int idx = k * 256 + tid;
        if (idx < 4256) ((int*)colmin)[idx] = INF_BITS;
    }
    if (tid < 128) rowmin[tid] = INF_BITS;
    __syncthreads();

    // A fragments: rows nt*128 + wr*64 + i*16 + c, 3 k-steps. Loaded once.
    const int rbA0 = b * 512 + nt * 8 + wr * 4;
    bhalf8 af[4][3];
    #pragma unroll
    for (int i = 0; i < 4; i++)
        #pragma unroll
        for (int ks = 0; ks < 3; ks++)
            af[i][ks] = *(const bhalf8*)(Ap + ((size_t)((rbA0 + i) * 3 + ks) * 64 + lane) * 8);

    f32x4 rv[4];                 // running row-min, rows i*16+q*4+r (this wave's 64 rows)
    #pragma unroll
    for (int i = 0; i < 4; i++) rv[i] = (f32x4){3.0e38f, 3.0e38f, 3.0e38f, 3.0e38f};

    const f32x4 zero4 = {0.f, 0.f, 0.f, 0.f};

    // step s: mt = mc*8 + s/2, rbB = b*512 + mt*8 + wc*4 + (s&1)*2; cols = wc*64+(s&1)*32+jj*16+c
    // pointers in shorts: rb stride 1536; per 2 steps advance 8 rb = 12288 shorts.
    const unsigned short* pE = Bp + (size_t)(b * 512 + mc * 64 + wc * 4) * 1536 + lane * 8;
    const unsigned short* pO = pE + 3072;   // (s&1)=1 -> +2 rb

    auto loadB = [&](const unsigned short* p, bhalf8 (&bf)[2][3]) {
        #pragma unroll
        for (int jj = 0; jj < 2; jj++)
            #pragma unroll
            for (int ks = 0; ks < 3; ks++)
                bf[jj][ks] = *(const bhalf8*)(p + jj * 1536 + ks * 512);
    };

    auto process = [&](int mtl, int half, bhalf8 (&bf)[2][3]) {
        f32x4 acc[4][2];
        #pragma unroll
        for (int i = 0; i < 4; i++)
            #pragma unroll
            for (int jj = 0; jj < 2; jj++)
                acc[i][jj] = __builtin_amdgcn_mfma_f32_16x16x32_bf16(af[i][0], bf[jj][0], zero4, 0, 0, 0);
        #pragma unroll
        for (int ks = 1; ks < 3; ks++)
            #pragma unroll
            for (int i = 0; i < 4; i++)
                #pragma unroll
                for (int jj = 0; jj < 2; jj++)
                    acc[i][jj] = __builtin_amdgcn_mfma_f32_16x16x32_bf16(af[i][ks], bf[jj][ks], acc[i][jj], 0, 0, 0);
        // acc[i][jj][r] = d(row nt*128+wr*64+i*16+q*4+r, col (mc*8+mtl)*128+wc*64+half*32+jj*16+c)

        // row-min: 16 v_min3
        #pragma unroll
        for (int i = 0; i < 4; i++)
            #pragma unroll
            for (int r = 0; r < 4; r++)
                rv[i][r] = fminf(fminf(acc[i][0][r], acc[i][1][r]), rv[i][r]);

        // col-min over this lane's 16 rows: balanced min3 tree (8 ops), then 1 ds_min per jj
        #pragma unroll
        for (int jj = 0; jj < 2; jj++) {
            float t0 = min3f(acc[0][jj][0], acc[0][jj][1], acc[0][jj][2]);
            float t1 = min3f(acc[0][jj][3], acc[1][jj][0], acc[1][jj][1]);
            float t2 = min3f(acc[1][jj][2], acc[1][jj][3], acc[2][jj][0]);
            float t3 = min3f(acc[2][jj][1], acc[2][jj][2], acc[2][jj][3]);
            float t4 = min3f(acc[3][jj][0], acc[3][jj][1], acc[3][jj][2]);
            float t  = fminf(min3f(t0, t1, t2), min3f(t3, t4, acc[3][jj][3]));
            atomicMin(&colmin[q][mtl * 132 + wc * 64 + half * 32 + jj * 16 + c], __float_as_int(t));
        }
    };

    bhalf8 bf0[2][3], bf1[2][3];
    loadB(pE, bf0);
    #pragma unroll 1
    for (int mtl = 0; mtl < 8; mtl++) {
        loadB(pO, bf1);
        process(mtl, 0, bf0);
        pE += 12288;
        if (mtl < 7) loadB(pE, bf0);
        process(mtl, 1, bf1);
        pO += 12288;
    }

    // flush register row-mins to LDS, then one global atomicMin per row / per col
    #pragma unroll
    for (int i = 0; i < 4; i++)
        #pragma unroll
        for (int r = 0; r < 4; r++)
            atomicMin(&rowmin[wr * 64 + i * 16 + q * 4 + r], __float_as_int(rv[i][r]));
    __syncthreads();

    if (tid < 128)
        atomicMin(&rowglob[(size_t)(b * 64 + nt) * 128 + tid], rowmin[tid]);
    #pragma unroll
    for (int k = 0; k < 4; k++) {
        const int idx = k * 256 + tid;       // 0..1023 = mtl*128 + col
        const int mtl = idx >> 7, col = idx & 127;
        int m = min(min(colmin[0][mtl * 132 + col], colmin[1][mtl * 132 + col]),
                    min(colmin[2][mtl * 132 + col], colmin[3][mtl * 132 + col]));
        atomicMin(&colglob[(size_t)(b * 64 + mc * 8 + mtl) * 128 + col], m);
    }
}

// ---------------- finalize: mean of rowglob + colglob (256 KB total) ----------------
__global__ __launch_bounds__(256) void chamfer_finalize(
        const int* __restrict__ rowglob, const int* __restrict__ colglob,
        float* __restrict__ out) {
    const int gid = blockIdx.x * 256 + threadIdx.x;   // 64 blocks -> 16384 threads
    float s = 0.f;
    #pragma unroll
    for (int k = 0; k < 2; k++) {
        s += __int_as_float(rowglob[gid + k * 16384]) * (1.0f / ((float)B_ * (float)N_));
        s += __int_as_float(colglob[gid + k * 16384]) * (1.0f / ((float)B_ * (float)M_));
    }
    __shared__ float sb[256];
    const int tid = threadIdx.x;
    sb[tid] = s;
    __syncthreads();
    for (int st = 128; st > 0; st >>= 1) {
        if (tid < st) sb[tid] += sb[tid + st];
        __syncthreads();
    }
    if (tid == 0) atomicAdd(out, sb[0]);
}

extern "C" void kernel_launch(void* const* d_in, const int* in_sizes, int n_in,
                              void* d_out, int out_size, void* d_ws, size_t ws_size,
                              hipStream_t stream) {
    const float* f  = (const float*)d_in[0];
    const float* f2 = (const float*)d_in[1];
    char* ws = (char*)d_ws;
    unsigned short* Ap = (unsigned short*)(ws + OFF_A);
    unsigned short* Bp = (unsigned short*)(ws + OFF_B);
    int* rowglob = (int*)(ws + OFF_RG);
    int* colglob = (int*)(ws + OFF_CG);
    float* out   = (float*)d_out;

    // prep: fragment layout + norm fusion; inits rowglob/colglob/out
    chamfer_prep<<<dim3(1024), dim3(256), 0, stream>>>(f, f2, Ap, Bp, rowglob, out);

    // main: 2048 blocks, wait-free 16-step loop
    chamfer_tile<<<dim3(8, NT_, B_), dim3(256), 0, stream>>>(Ap, Bp, rowglob, colglob);

    // finalize: 256 KB read + block sums -> scalar
    chamfer_finalize<<<dim3(64), dim3(256), 0, stream>>>(rowglob, colglob, out);
}